// Round 1
// baseline (3189.192 us; speedup 1.0000x reference)
//
#include <hip/hip_runtime.h>

#define N_NODES 20000
#define N_EDGES 160000
#define TILE_E 32
#define EBLK (N_EDGES / TILE_E)

#define C0f   0.14433756729740643f   // sqrt(1/48)
#define C1f   0.21650635094610965f   // sqrt(3/64)
#define IS3   0.5773502691896258f    // 1/sqrt(3)
#define IS6   0.4082482904638631f    // 1/sqrt(6)
#define EPS_LN 1e-5f

__device__ __forceinline__ float shfl_x16(float v) { return __shfl_xor(v, 16, 64); }

// Fused: gather x by dst, MLP1 (LDS), MLP2 streamed in 32-col chunks from L2,
// tensor-product contraction into register accumulators, atomic scatter by src.
__global__ __launch_bounds__(256)
void edge_kernel(const float* __restrict__ node_attr,
                 const float* __restrict__ edge_attr,
                 const float* __restrict__ edge_sh,
                 const float* __restrict__ fc_w1,
                 const float* __restrict__ fc_b1,
                 const float* __restrict__ fc_w2,
                 const float* __restrict__ fc_b2,
                 const int*   __restrict__ edge_index,
                 float* __restrict__ accum,   // d_out as accumulator (N*80), pre-zeroed
                 float* __restrict__ cnt)     // ws (N floats), pre-zeroed
{
    __shared__ float s_u[TILE_E * 128];      // edge_attr tile, later W2 chunk [128][32]
    __shared__ float s_h[TILE_E][128];       // hidden activations
    __shared__ float s_x0[TILE_E][32];
    __shared__ float s_x1[TILE_E][48];       // [u*3+i]
    __shared__ float s_x1d[TILE_E][16];      // dot(x1[u], sh1)
    __shared__ float s_cr[TILE_E][48];       // cross(x1[u], sh1)
    __shared__ float s_sh[TILE_E][4];
    __shared__ int   s_src[TILE_E];
    __shared__ int   s_dst[TILE_E];

    const int tid = threadIdx.x;
    const int e0  = blockIdx.x * TILE_E;

    // ---- A1: indices, sh, edge_attr tile ----
    if (tid < TILE_E) {
        int s = edge_index[e0 + tid];
        int d = edge_index[N_EDGES + e0 + tid];
        s_src[tid] = s;
        s_dst[tid] = d;
        atomicAdd(&cnt[s], 1.0f);
    }
    if (tid < TILE_E * 4) {
        int e = tid >> 2, c = tid & 3;
        s_sh[e][c] = edge_sh[(e0 + e) * 4 + c];
    }
    {
        const float4* ga = (const float4*)(edge_attr + (size_t)e0 * 128);
        float4* su4 = (float4*)s_u;
        #pragma unroll
        for (int i = 0; i < 4; ++i) su4[tid + i * 256] = ga[tid + i * 256];
    }
    __syncthreads();

    // ---- A2: gather x = node_attr[dst] ----
    #pragma unroll
    for (int i = 0; i < 10; ++i) {
        int f = tid + i * 256;
        int e = f / 80, c = f % 80;
        float v = node_attr[(size_t)s_dst[e] * 80 + c];
        if (c < 32) s_x0[e][c] = v;
        else        s_x1[e][c - 32] = v;
    }
    __syncthreads();

    // ---- A3a: x1.sh1 dot and cross products (32*16 items) ----
    #pragma unroll
    for (int i = 0; i < 2; ++i) {
        int it = tid + i * 256;
        int e = it >> 4, u = it & 15;
        float x0v = s_x1[e][u*3+0], x1v = s_x1[e][u*3+1], x2v = s_x1[e][u*3+2];
        float a = s_sh[e][1], b = s_sh[e][2], c = s_sh[e][3];
        s_x1d[e][u]    = x0v*a + x1v*b + x2v*c;
        s_cr[e][u*3+0] = x1v*c - x2v*b;
        s_cr[e][u*3+1] = x2v*a - x0v*c;
        s_cr[e][u*3+2] = x0v*b - x1v*a;
    }

    // ---- A3b: h = relu(ea @ W1 + b1); thread = (j, eb), 16 edges each ----
    {
        int j  = tid & 127;
        int eb = tid >> 7;   // 0/1
        float acc[16];
        #pragma unroll
        for (int r = 0; r < 16; ++r) acc[r] = 0.f;
        for (int c = 0; c < 128; ++c) {
            float w1v = fc_w1[c * 128 + j];
            #pragma unroll
            for (int r = 0; r < 16; ++r)
                acc[r] += s_u[(eb + 2 * r) * 128 + c] * w1v;
        }
        float b = fc_b1[j];
        #pragma unroll
        for (int r = 0; r < 16; ++r)
            s_h[eb + 2 * r][j] = fmaxf(acc[r] + b, 0.f);
    }

    // ---- chunk loop: 80 chunks of 32 W2 columns ----
    const int jj    = tid & 31;
    const int ebase = tid >> 5;   // 0..7; edges ebase, +8, +16, +24
    float racc0[4] = {0.f, 0.f, 0.f, 0.f};
    float racc1[4] = {0.f, 0.f, 0.f, 0.f};
    float racc3[4] = {0.f, 0.f, 0.f, 0.f};
    float racc4[4][3];
    float racc5[4][3];
    #pragma unroll
    for (int r = 0; r < 4; ++r)
        #pragma unroll
        for (int i = 0; i < 3; ++i) { racc4[r][i] = 0.f; racc5[r][i] = 0.f; }

    for (int ch = 0; ch < 80; ++ch) {
        __syncthreads();   // protect s_u readers (h-phase / prev chunk)
        {   // load W2[:, ch*32 : ch*32+32] into s_u as [k][jj]
            const float4* gw = (const float4*)(fc_w2 + ch * 32);
            float4* su4 = (float4*)s_u;
            #pragma unroll
            for (int i = 0; i < 4; ++i) {
                int f4 = tid + i * 256;
                int k = f4 >> 3, q = f4 & 7;
                su4[f4] = gw[k * 640 + q];
            }
        }
        __syncthreads();

        float b2j = fc_b2[ch * 32 + jj];
        float wv0 = b2j, wv1 = b2j, wv2 = b2j, wv3 = b2j;
        #pragma unroll 4
        for (int k = 0; k < 128; k += 4) {
            float a0 = s_u[(k + 0) * 32 + jj];
            float a1 = s_u[(k + 1) * 32 + jj];
            float a2 = s_u[(k + 2) * 32 + jj];
            float a3 = s_u[(k + 3) * 32 + jj];
            const float4 h0 = *(const float4*)&s_h[ebase     ][k];
            const float4 h1 = *(const float4*)&s_h[ebase +  8][k];
            const float4 h2 = *(const float4*)&s_h[ebase + 16][k];
            const float4 h3 = *(const float4*)&s_h[ebase + 24][k];
            wv0 += h0.x * a0 + h0.y * a1 + h0.z * a2 + h0.w * a3;
            wv1 += h1.x * a0 + h1.y * a1 + h1.z * a2 + h1.w * a3;
            wv2 += h2.x * a0 + h2.y * a1 + h2.z * a2 + h2.w * a3;
            wv3 += h3.x * a0 + h3.y * a1 + h3.z * a2 + h3.w * a3;
        }
        float wv[4] = {wv0, wv1, wv2, wv3};

        if (ch < 32) {                       // w1[u=ch][w_=jj] -> out0
            int u = ch;
            #pragma unroll
            for (int r = 0; r < 4; ++r) racc0[r] += s_x0[ebase + 8*r][u] * wv[r];
        } else if (ch < 48) {                // w2[u][w_=jj] -> out0
            int u = ch - 32;
            #pragma unroll
            for (int r = 0; r < 4; ++r) racc1[r] += s_x1d[ebase + 8*r][u] * wv[r];
        } else if (ch < 64) {                // w3[u][w_=jj&15] -> out1a
            int u = ((ch - 48) << 1) | (jj >> 4);
            #pragma unroll
            for (int r = 0; r < 4; ++r) racc3[r] += s_x0[ebase + 8*r][u] * wv[r];
        } else if (ch < 72) {                // w4 -> out1b
            int u = ((ch - 64) << 1) | (jj >> 4);
            #pragma unroll
            for (int r = 0; r < 4; ++r)
                #pragma unroll
                for (int i = 0; i < 3; ++i)
                    racc4[r][i] += s_x1[ebase + 8*r][u*3 + i] * wv[r];
        } else {                             // w5 -> out1c (cross term)
            int u = ((ch - 72) << 1) | (jj >> 4);
            #pragma unroll
            for (int r = 0; r < 4; ++r)
                #pragma unroll
                for (int i = 0; i < 3; ++i)
                    racc5[r][i] += s_cr[ebase + 8*r][u*3 + i] * wv[r];
        }
    }

    // ---- epilogue: combine + atomic scatter by src ----
    #pragma unroll
    for (int r = 0; r < 4; ++r) {
        int e = ebase + 8 * r;
        float sh0 = s_sh[e][0];
        float o0  = C0f * (sh0 * racc0[r] + IS3 * racc1[r]);
        int obase = s_src[e] * 80;
        atomicAdd(&accum[obase + jj], o0);
        // combine the two 16-lane halves (u parity split for w3/w4/w5)
        float v3  = racc3[r]    + shfl_x16(racc3[r]);
        float v40 = racc4[r][0] + shfl_x16(racc4[r][0]);
        float v41 = racc4[r][1] + shfl_x16(racc4[r][1]);
        float v42 = racc4[r][2] + shfl_x16(racc4[r][2]);
        float v50 = racc5[r][0] + shfl_x16(racc5[r][0]);
        float v51 = racc5[r][1] + shfl_x16(racc5[r][1]);
        float v52 = racc5[r][2] + shfl_x16(racc5[r][2]);
        if (jj < 16) {
            float a = s_sh[e][1], b = s_sh[e][2], c = s_sh[e][3];
            float o1_0 = C1f * (IS3 * a * v3 + IS3 * sh0 * v40 + IS6 * v50);
            float o1_1 = C1f * (IS3 * b * v3 + IS3 * sh0 * v41 + IS6 * v51);
            float o1_2 = C1f * (IS3 * c * v3 + IS3 * sh0 * v42 + IS6 * v52);
            atomicAdd(&accum[obase + 32 + jj * 3 + 0], o1_0);
            atomicAdd(&accum[obase + 32 + jj * 3 + 1], o1_1);
            atomicAdd(&accum[obase + 32 + jj * 3 + 2], o1_2);
        }
    }
}

// Per-node: mean-divide, residual, equivariant layernorm. In-place on d_out.
__global__ __launch_bounds__(256)
void node_kernel(const float* __restrict__ node_attr,
                 const float* __restrict__ mean_shift,  // 48
                 const float* __restrict__ aw,          // 48
                 const float* __restrict__ ab,          // 32
                 const float* __restrict__ cnt,
                 float* __restrict__ out)
{
    int n = blockIdx.x * blockDim.x + threadIdx.x;
    if (n >= N_NODES) return;
    float inv = 1.0f / fmaxf(cnt[n], 1.0f);
    size_t base = (size_t)n * 80;
    float v[80];
    #pragma unroll
    for (int i = 0; i < 80; ++i) v[i] = out[base + i] * inv + node_attr[base + i];

    // f0: scalar channels
    float m0 = 0.f;
    #pragma unroll
    for (int u = 0; u < 32; ++u) m0 += v[u];
    m0 *= (1.0f / 32.0f);
    float n0 = 0.f;
    #pragma unroll
    for (int u = 0; u < 32; ++u) {
        float f = v[u] - m0 * mean_shift[u];
        v[u] = f;
        n0 += f * f;
    }
    n0 = rsqrtf(n0 * (1.0f / 32.0f) + EPS_LN);
    #pragma unroll
    for (int u = 0; u < 32; ++u) out[base + u] = v[u] * (n0 * aw[u]) + ab[u];

    // f1: vector channels
    float m1[3] = {0.f, 0.f, 0.f};
    #pragma unroll
    for (int u = 0; u < 16; ++u)
        #pragma unroll
        for (int i = 0; i < 3; ++i) m1[i] += v[32 + u*3 + i];
    #pragma unroll
    for (int i = 0; i < 3; ++i) m1[i] *= (1.0f / 16.0f);
    float n1 = 0.f;
    #pragma unroll
    for (int u = 0; u < 16; ++u)
        #pragma unroll
        for (int i = 0; i < 3; ++i) {
            float f = v[32 + u*3 + i] - m1[i] * mean_shift[32 + u];
            v[32 + u*3 + i] = f;
            n1 += f * f;
        }
    n1 = rsqrtf(n1 * (1.0f / 48.0f) + EPS_LN);
    #pragma unroll
    for (int u = 0; u < 16; ++u)
        #pragma unroll
        for (int i = 0; i < 3; ++i)
            out[base + 32 + u*3 + i] = v[32 + u*3 + i] * (n1 * aw[32 + u]);
}

extern "C" void kernel_launch(void* const* d_in, const int* in_sizes, int n_in,
                              void* d_out, int out_size, void* d_ws, size_t ws_size,
                              hipStream_t stream) {
    const float* node_attr  = (const float*)d_in[0];
    const float* edge_attr  = (const float*)d_in[1];
    const float* edge_sh    = (const float*)d_in[2];
    const float* fc_w1      = (const float*)d_in[3];
    const float* fc_b1      = (const float*)d_in[4];
    const float* fc_w2      = (const float*)d_in[5];
    const float* fc_b2      = (const float*)d_in[6];
    const float* mean_shift = (const float*)d_in[7];
    const float* aw         = (const float*)d_in[8];
    const float* ab         = (const float*)d_in[9];
    const int*   edge_index = (const int*)d_in[10];
    float* out = (float*)d_out;
    float* cnt = (float*)d_ws;

    // d_out doubles as the scatter accumulator; cnt lives in ws. Both are
    // re-poisoned to 0xAA before every timed launch -> zero them here.
    hipMemsetAsync(d_out, 0, (size_t)N_NODES * 80 * sizeof(float), stream);
    hipMemsetAsync(d_ws, 0, (size_t)N_NODES * sizeof(float), stream);

    edge_kernel<<<EBLK, 256, 0, stream>>>(node_attr, edge_attr, edge_sh,
                                          fc_w1, fc_b1, fc_w2, fc_b2,
                                          edge_index, out, cnt);
    node_kernel<<<(N_NODES + 255) / 256, 256, 0, stream>>>(node_attr, mean_shift,
                                                           aw, ab, cnt, out);
}

// Round 2
// 596.823 us; speedup vs baseline: 5.3436x; 5.3436x over previous
//
#include <hip/hip_runtime.h>

typedef __attribute__((ext_vector_type(8))) short short8;
typedef __attribute__((ext_vector_type(4))) float floatx4;

#define N_NODES 20000
#define N_EDGES 160000
#define TILE_E 64
#define EBLK (N_EDGES / TILE_E)   // 2500

#define C0f   0.14433756729740643f   // sqrt(1/48)
#define C1f   0.21650635094610965f   // sqrt(3/64)
#define IS3   0.5773502691896258f    // 1/sqrt(3)
#define IS6   0.4082482904638631f    // 1/sqrt(6)
#define EPS_LN 1e-5f

// ws layout (bytes): [0, 34816) W1^T bf16 [128][136]; [34816, 731136) W2^T bf16
// [2560][136]; [731136, 811136) cnt (N_NODES floats). Pad 136 keeps b128 LDS/
// global fragment reads 2-way-bank at worst (free) and rows 16B-aligned.
#define W1T_OFF 0
#define W2T_OFF 34816
#define CNT_OFF 731136

__device__ __forceinline__ short f2bf(float f) {   // fp32 -> bf16 RNE
    unsigned u = __float_as_uint(f);
    u += 0x7fff + ((u >> 16) & 1);
    return (short)(u >> 16);
}

__device__ __forceinline__ short8 load8_bf16(const float* p) {
    const float4* q = (const float4*)p;
    float4 f0 = q[0], f1 = q[1];
    short8 s;
    s[0]=f2bf(f0.x); s[1]=f2bf(f0.y); s[2]=f2bf(f0.z); s[3]=f2bf(f0.w);
    s[4]=f2bf(f1.x); s[5]=f2bf(f1.y); s[6]=f2bf(f1.z); s[7]=f2bf(f1.w);
    return s;
}

// Transpose+convert W1 (128x128) and W2 (128x2560) to bf16 [n][136] layouts.
__global__ __launch_bounds__(256)
void prep_kernel(const float* __restrict__ fc_w1, const float* __restrict__ fc_w2,
                 short* __restrict__ w1t, short* __restrict__ w2t) {
    int idx = blockIdx.x * 256 + threadIdx.x;
    if (idx < 128 * 128) {
        int k = idx >> 7, n = idx & 127;
        w1t[n * 136 + k] = f2bf(fc_w1[idx]);
    }
    int idx2 = idx - 128 * 128;
    if (idx2 >= 0 && idx2 < 128 * 2560) {
        int k = idx2 / 2560, n = idx2 % 2560;
        w2t[n * 136 + k] = f2bf(fc_w2[idx2]);
    }
}

__global__ __launch_bounds__(256, 2)
void edge_kernel(const float* __restrict__ node_attr,
                 const float* __restrict__ edge_attr,
                 const float* __restrict__ edge_sh,
                 const float* __restrict__ fc_b1,
                 const float* __restrict__ fc_b2,
                 const int*   __restrict__ edge_index,
                 const short* __restrict__ w1t,
                 const short* __restrict__ w2t,
                 float* __restrict__ accum,   // d_out, pre-zeroed
                 float* __restrict__ cnt)     // pre-zeroed
{
    __shared__ short s_H[64 * 136];     // hidden activations bf16, wave-private rows
    __shared__ float s_x0[64 * 33];     // +1 pad: broadcast groups hit distinct banks
    __shared__ float s_x1[64 * 49];
    __shared__ float s_x1d[64 * 17];
    __shared__ float s_cr[64 * 49];
    __shared__ float s_sh[64 * 4];
    __shared__ int   s_src[64];
    __shared__ int   s_dst[64];

    const int tid = threadIdx.x;
    const int e0  = blockIdx.x * TILE_E;

    // ---- phase A: indices, sh, gather, derived arrays ----
    if (tid < 64) {
        int s = edge_index[e0 + tid];
        int d = edge_index[N_EDGES + e0 + tid];
        s_src[tid] = s; s_dst[tid] = d;
        atomicAdd(&cnt[s], 1.0f);
    }
    s_sh[tid] = edge_sh[(size_t)e0 * 4 + tid];   // 64 edges x 4 = 256 = blockDim
    __syncthreads();

    #pragma unroll
    for (int i = 0; i < 20; ++i) {
        int f = tid + i * 256;
        int e = f / 80, c = f % 80;
        float v = node_attr[(size_t)s_dst[e] * 80 + c];
        if (c < 32) s_x0[e * 33 + c] = v;
        else        s_x1[e * 49 + (c - 32)] = v;
    }
    __syncthreads();

    #pragma unroll
    for (int i = 0; i < 4; ++i) {
        int it = tid + i * 256;
        int e = it >> 4, u = it & 15;
        float X = s_x1[e*49 + u*3], Y = s_x1[e*49 + u*3 + 1], Z = s_x1[e*49 + u*3 + 2];
        float a = s_sh[e*4 + 1], b = s_sh[e*4 + 2], c = s_sh[e*4 + 3];
        s_x1d[e*17 + u]    = X*a + Y*b + Z*c;
        s_cr[e*49 + u*3]   = Y*c - Z*b;
        s_cr[e*49 + u*3+1] = Z*a - X*c;
        s_cr[e*49 + u*3+2] = X*b - Y*a;
    }
    __syncthreads();

    // ---- per-wave identity ----
    const int lane  = tid & 63;
    const int wv    = tid >> 6;        // wave 0..3, owns edges [wv*16, wv*16+16)
    const int ew    = wv * 16;
    const int ln    = lane & 15;       // MFMA col / A-row selector
    const int qd    = lane >> 4;       // quad
    const int rbase = ew + qd * 4;     // local edge base for C rows

    // ---- MLP1: h = relu(EA @ W1 + b1), MFMA, write bf16 to s_H ----
    {
        short8 a1[4];
        const float* ap = edge_attr + (size_t)(e0 + ew + ln) * 128 + qd * 8;
        #pragma unroll
        for (int kt = 0; kt < 4; ++kt) a1[kt] = load8_bf16(ap + kt * 32);

        #pragma unroll
        for (int t = 0; t < 8; ++t) {
            const short* bp = w1t + (t * 16 + ln) * 136 + qd * 8;
            short8 b0 = *(const short8*)bp;
            short8 b1 = *(const short8*)(bp + 32);
            short8 b2 = *(const short8*)(bp + 64);
            short8 b3 = *(const short8*)(bp + 96);
            floatx4 C = {0.f, 0.f, 0.f, 0.f};
            C = __builtin_amdgcn_mfma_f32_16x16x32_bf16(a1[0], b0, C, 0, 0, 0);
            C = __builtin_amdgcn_mfma_f32_16x16x32_bf16(a1[1], b1, C, 0, 0, 0);
            C = __builtin_amdgcn_mfma_f32_16x16x32_bf16(a1[2], b2, C, 0, 0, 0);
            C = __builtin_amdgcn_mfma_f32_16x16x32_bf16(a1[3], b3, C, 0, 0, 0);
            int n = t * 16 + ln;
            float bias = fc_b1[n];
            #pragma unroll
            for (int r = 0; r < 4; ++r) {
                float h = fmaxf(C[r] + bias, 0.f);
                s_H[(rbase + r) * 136 + n] = f2bf(h);
            }
        }
    }
    __syncthreads();   // cheap safety: s_H write -> cross-lane read ordering

    // A2 fragments (stay in registers for the whole main loop)
    short8 a2[4];
    {
        const short* hp = s_H + (ew + ln) * 136 + qd * 8;
        #pragma unroll
        for (int kt = 0; kt < 4; ++kt) a2[kt] = *(const short8*)(hp + kt * 32);
    }

    // ---- main loop: 160 N-tiles, no barriers ----
    float r0lo[4] = {0,0,0,0}, r0hi[4] = {0,0,0,0};
    float r1lo[4] = {0,0,0,0}, r1hi[4] = {0,0,0,0};
    float r3[4]   = {0,0,0,0};
    float r4[4][3] = {{0,0,0},{0,0,0},{0,0,0},{0,0,0}};
    float r5[4][3] = {{0,0,0},{0,0,0},{0,0,0},{0,0,0}};

    auto tileC = [&](int t) -> floatx4 {
        const short* bp = w2t + (t * 16 + ln) * 136 + qd * 8;
        short8 b0 = *(const short8*)bp;
        short8 b1 = *(const short8*)(bp + 32);
        short8 b2 = *(const short8*)(bp + 64);
        short8 b3 = *(const short8*)(bp + 96);
        floatx4 C = {0.f, 0.f, 0.f, 0.f};
        C = __builtin_amdgcn_mfma_f32_16x16x32_bf16(a2[0], b0, C, 0, 0, 0);
        C = __builtin_amdgcn_mfma_f32_16x16x32_bf16(a2[1], b1, C, 0, 0, 0);
        C = __builtin_amdgcn_mfma_f32_16x16x32_bf16(a2[2], b2, C, 0, 0, 0);
        C = __builtin_amdgcn_mfma_f32_16x16x32_bf16(a2[3], b3, C, 0, 0, 0);
        float bias = fc_b2[t * 16 + ln];
        C[0] += bias; C[1] += bias; C[2] += bias; C[3] += bias;
        return C;
    };

    // region 1: w1[u<32][w<32] -> out0          (tiles 0..63)
    for (int u = 0; u < 32; ++u) {
        floatx4 Clo = tileC(2 * u);
        floatx4 Chi = tileC(2 * u + 1);
        #pragma unroll
        for (int r = 0; r < 4; ++r) {
            float a = s_x0[(rbase + r) * 33 + u];
            r0lo[r] += a * Clo[r];
            r0hi[r] += a * Chi[r];
        }
    }
    // region 2: w2[u<16][w<32] -> out0          (tiles 64..95)
    for (int u = 0; u < 16; ++u) {
        floatx4 Clo = tileC(64 + 2 * u);
        floatx4 Chi = tileC(65 + 2 * u);
        #pragma unroll
        for (int r = 0; r < 4; ++r) {
            float a = s_x1d[(rbase + r) * 17 + u];
            r1lo[r] += a * Clo[r];
            r1hi[r] += a * Chi[r];
        }
    }
    // region 3: w3[u<32][w<16] -> out1 (sh1 term)  (tiles 96..127)
    for (int u = 0; u < 32; ++u) {
        floatx4 C = tileC(96 + u);
        #pragma unroll
        for (int r = 0; r < 4; ++r)
            r3[r] += s_x0[(rbase + r) * 33 + u] * C[r];
    }
    // region 4: w4[u<16][w<16] -> out1 (sh0 term)  (tiles 128..143)
    for (int u = 0; u < 16; ++u) {
        floatx4 C = tileC(128 + u);
        #pragma unroll
        for (int r = 0; r < 4; ++r) {
            const float* xp = &s_x1[(rbase + r) * 49 + u * 3];
            r4[r][0] += xp[0] * C[r];
            r4[r][1] += xp[1] * C[r];
            r4[r][2] += xp[2] * C[r];
        }
    }
    // region 5: w5[u<16][w<16] -> out1 (cross term)  (tiles 144..159)
    for (int u = 0; u < 16; ++u) {
        floatx4 C = tileC(144 + u);
        #pragma unroll
        for (int r = 0; r < 4; ++r) {
            const float* xp = &s_cr[(rbase + r) * 49 + u * 3];
            r5[r][0] += xp[0] * C[r];
            r5[r][1] += xp[1] * C[r];
            r5[r][2] += xp[2] * C[r];
        }
    }

    // ---- epilogue: atomic scatter by src ----
    #pragma unroll
    for (int r = 0; r < 4; ++r) {
        int e = rbase + r;
        float sh0 = s_sh[e*4], sa = s_sh[e*4+1], sb = s_sh[e*4+2], sc = s_sh[e*4+3];
        int base = s_src[e] * 80;
        atomicAdd(&accum[base + ln],      C0f * (sh0 * r0lo[r] + IS3 * r1lo[r]));
        atomicAdd(&accum[base + 16 + ln], C0f * (sh0 * r0hi[r] + IS3 * r1hi[r]));
        float t3 = C1f * IS3 * r3[r];
        float s0 = C1f * IS3 * sh0;
        float c6 = C1f * IS6;
        atomicAdd(&accum[base + 32 + ln*3 + 0], sa * t3 + s0 * r4[r][0] + c6 * r5[r][0]);
        atomicAdd(&accum[base + 32 + ln*3 + 1], sb * t3 + s0 * r4[r][1] + c6 * r5[r][1]);
        atomicAdd(&accum[base + 32 + ln*3 + 2], sc * t3 + s0 * r4[r][2] + c6 * r5[r][2]);
    }
}

// Per-node: mean-divide, residual, equivariant layernorm. In-place on d_out.
__global__ __launch_bounds__(256)
void node_kernel(const float* __restrict__ node_attr,
                 const float* __restrict__ mean_shift,
                 const float* __restrict__ aw,
                 const float* __restrict__ ab,
                 const float* __restrict__ cnt,
                 float* __restrict__ out)
{
    int n = blockIdx.x * blockDim.x + threadIdx.x;
    if (n >= N_NODES) return;
    float inv = 1.0f / fmaxf(cnt[n], 1.0f);
    size_t base = (size_t)n * 80;
    float v[80];
    #pragma unroll
    for (int i = 0; i < 80; ++i) v[i] = out[base + i] * inv + node_attr[base + i];

    float m0 = 0.f;
    #pragma unroll
    for (int u = 0; u < 32; ++u) m0 += v[u];
    m0 *= (1.0f / 32.0f);
    float n0 = 0.f;
    #pragma unroll
    for (int u = 0; u < 32; ++u) {
        float f = v[u] - m0 * mean_shift[u];
        v[u] = f;
        n0 += f * f;
    }
    n0 = rsqrtf(n0 * (1.0f / 32.0f) + EPS_LN);
    #pragma unroll
    for (int u = 0; u < 32; ++u) out[base + u] = v[u] * (n0 * aw[u]) + ab[u];

    float m1[3] = {0.f, 0.f, 0.f};
    #pragma unroll
    for (int u = 0; u < 16; ++u)
        #pragma unroll
        for (int i = 0; i < 3; ++i) m1[i] += v[32 + u*3 + i];
    #pragma unroll
    for (int i = 0; i < 3; ++i) m1[i] *= (1.0f / 16.0f);
    float n1 = 0.f;
    #pragma unroll
    for (int u = 0; u < 16; ++u)
        #pragma unroll
        for (int i = 0; i < 3; ++i) {
            float f = v[32 + u*3 + i] - m1[i] * mean_shift[32 + u];
            v[32 + u*3 + i] = f;
            n1 += f * f;
        }
    n1 = rsqrtf(n1 * (1.0f / 48.0f) + EPS_LN);
    #pragma unroll
    for (int u = 0; u < 16; ++u)
        #pragma unroll
        for (int i = 0; i < 3; ++i)
            out[base + 32 + u*3 + i] = v[32 + u*3 + i] * (n1 * aw[32 + u]);
}

extern "C" void kernel_launch(void* const* d_in, const int* in_sizes, int n_in,
                              void* d_out, int out_size, void* d_ws, size_t ws_size,
                              hipStream_t stream) {
    const float* node_attr  = (const float*)d_in[0];
    const float* edge_attr  = (const float*)d_in[1];
    const float* edge_sh    = (const float*)d_in[2];
    const float* fc_w1      = (const float*)d_in[3];
    const float* fc_b1      = (const float*)d_in[4];
    const float* fc_w2      = (const float*)d_in[5];
    const float* fc_b2      = (const float*)d_in[6];
    const float* mean_shift = (const float*)d_in[7];
    const float* aw         = (const float*)d_in[8];
    const float* ab         = (const float*)d_in[9];
    const int*   edge_index = (const int*)d_in[10];
    float* out = (float*)d_out;

    short* w1t = (short*)((char*)d_ws + W1T_OFF);
    short* w2t = (short*)((char*)d_ws + W2T_OFF);
    float* cnt = (float*)((char*)d_ws + CNT_OFF);

    hipMemsetAsync(d_out, 0, (size_t)N_NODES * 80 * sizeof(float), stream);
    hipMemsetAsync(cnt, 0, (size_t)N_NODES * sizeof(float), stream);

    prep_kernel<<<(128*128 + 128*2560 + 255) / 256, 256, 0, stream>>>(fc_w1, fc_w2, w1t, w2t);
    edge_kernel<<<EBLK, 256, 0, stream>>>(node_attr, edge_attr, edge_sh,
                                          fc_b1, fc_b2, edge_index,
                                          w1t, w2t, out, cnt);
    node_kernel<<<(N_NODES + 255) / 256, 256, 0, stream>>>(node_attr, mean_shift,
                                                           aw, ab, cnt, out);
}

// Round 3
// 426.362 us; speedup vs baseline: 7.4800x; 1.3998x over previous
//
#include <hip/hip_runtime.h>

typedef __attribute__((ext_vector_type(8))) short short8;
typedef __attribute__((ext_vector_type(4))) float floatx4;

#define N_NODES 20000
#define N_EDGES 160000
#define TILE_E 64
#define EBLK (N_EDGES / TILE_E)   // 2500

#define C0f   0.14433756729740643f   // sqrt(1/48)
#define C1f   0.21650635094610965f   // sqrt(3/64)
#define IS3   0.5773502691896258f    // 1/sqrt(3)
#define IS6   0.4082482904638631f    // 1/sqrt(6)
#define EPS_LN 1e-5f

// ws layout (bytes):
//   [0, 32768)        w1f: W1 bf16 in MFMA B-frag order, 2048 groups of 16B
//   [32768, 688128)   w2f: W2 bf16 in B-frag order, 40960 groups of 16B
//   [688128, 768128)  cnt: N_NODES floats
// Fragment order: group g = (t*4+kt)*64 + qd*16 + ln holds
// W^T[n=t*16+ln][k = kt*32 + qd*8 + j], j=0..7 -> lane (qd*16+ln) loads its
// 16B at base + lane*16: fully coalesced 1KB/wave per (tile,kt).
#define W1F_OFF 0
#define W2F_OFF 32768
#define CNT_OFF 688128

__device__ __forceinline__ short f2bf(float f) {   // fp32 -> bf16 RNE
    unsigned u = __float_as_uint(f);
    u += 0x7fff + ((u >> 16) & 1);
    return (short)(u >> 16);
}

__device__ __forceinline__ short8 load8_bf16(const float* p) {
    const float4* q = (const float4*)p;
    float4 f0 = q[0], f1 = q[1];
    short8 s;
    s[0]=f2bf(f0.x); s[1]=f2bf(f0.y); s[2]=f2bf(f0.z); s[3]=f2bf(f0.w);
    s[4]=f2bf(f1.x); s[5]=f2bf(f1.y); s[6]=f2bf(f1.z); s[7]=f2bf(f1.w);
    return s;
}

// Write W1/W2 into bf16 fragment-ordered layouts. One thread = one 16B group.
__global__ __launch_bounds__(256)
void prep_kernel(const float* __restrict__ fc_w1, const float* __restrict__ fc_w2,
                 short* __restrict__ w1f, short* __restrict__ w2f) {
    int g = blockIdx.x * 256 + threadIdx.x;
    if (g < 2048) {                      // W1: t<8, kt<4
        int ln = g & 15, qd = (g >> 4) & 3, kt = (g >> 6) & 3, t = g >> 8;
        int n = t * 16 + ln, kb = kt * 32 + qd * 8;
        short8 s;
        #pragma unroll
        for (int j = 0; j < 8; ++j) s[j] = f2bf(fc_w1[(kb + j) * 128 + n]);
        *(short8*)(w1f + g * 8) = s;
        return;
    }
    int g2 = g - 2048;
    if (g2 < 40960) {                    // W2: t<160, kt<4
        int ln = g2 & 15, qd = (g2 >> 4) & 3, kt = (g2 >> 6) & 3, t = g2 >> 8;
        int n = t * 16 + ln, kb = kt * 32 + qd * 8;
        short8 s;
        #pragma unroll
        for (int j = 0; j < 8; ++j) s[j] = f2bf(fc_w2[(kb + j) * 2560 + n]);
        *(short8*)(w2f + g2 * 8) = s;
    }
}

__global__ __launch_bounds__(256, 3)
void edge_kernel(const float* __restrict__ node_attr,
                 const float* __restrict__ edge_attr,
                 const float* __restrict__ edge_sh,
                 const float* __restrict__ fc_b1,
                 const float* __restrict__ fc_b2,
                 const int*   __restrict__ edge_index,
                 const short* __restrict__ w1f,
                 const short* __restrict__ w2f,
                 float* __restrict__ accum,   // d_out, pre-zeroed
                 float* __restrict__ cnt)     // pre-zeroed
{
    __shared__ short s_H[64 * 136];     // hidden activations bf16
    __shared__ float s_x0[64 * 33];     // pads keep quad-broadcast rows on distinct banks
    __shared__ float s_x1[64 * 49];
    __shared__ float s_x1d[64 * 17];
    __shared__ float s_sh[64 * 4];
    __shared__ int   s_src[64];
    __shared__ int   s_dst[64];

    const int tid = threadIdx.x;
    const int e0  = blockIdx.x * TILE_E;

    // ---- phase A: indices, sh, gather, x1.sh1 dot ----
    if (tid < 64) {
        int s = edge_index[e0 + tid];
        int d = edge_index[N_EDGES + e0 + tid];
        s_src[tid] = s; s_dst[tid] = d;
        atomicAdd(&cnt[s], 1.0f);
    }
    s_sh[tid] = edge_sh[(size_t)e0 * 4 + tid];
    __syncthreads();

    #pragma unroll
    for (int i = 0; i < 20; ++i) {
        int f = tid + i * 256;
        int e = f / 80, c = f % 80;
        float v = node_attr[(size_t)s_dst[e] * 80 + c];
        if (c < 32) s_x0[e * 33 + c] = v;
        else        s_x1[e * 49 + (c - 32)] = v;
    }
    __syncthreads();

    #pragma unroll
    for (int i = 0; i < 4; ++i) {
        int it = tid + i * 256;
        int e = it >> 4, u = it & 15;
        float X = s_x1[e*49 + u*3], Y = s_x1[e*49 + u*3 + 1], Z = s_x1[e*49 + u*3 + 2];
        s_x1d[e*17 + u] = X * s_sh[e*4+1] + Y * s_sh[e*4+2] + Z * s_sh[e*4+3];
    }
    __syncthreads();

    // ---- per-wave identity ----
    const int lane  = tid & 63;
    const int wv    = tid >> 6;        // wave owns edges [wv*16, wv*16+16)
    const int ew    = wv * 16;
    const int ln    = lane & 15;
    const int qd    = lane >> 4;
    const int rbase = ew + qd * 4;

    // ---- MLP1: h = relu(EA @ W1 + b1) via MFMA, bf16 to s_H ----
    {
        short8 a1[4];
        const float* ap = edge_attr + (size_t)(e0 + ew + ln) * 128 + qd * 8;
        #pragma unroll
        for (int kt = 0; kt < 4; ++kt) a1[kt] = load8_bf16(ap + kt * 32);

        #pragma unroll
        for (int t = 0; t < 8; ++t) {
            const short* bp = w1f + (size_t)(t * 4) * 512 + lane * 8;
            short8 b0 = *(const short8*)bp;
            short8 b1 = *(const short8*)(bp + 512);
            short8 b2 = *(const short8*)(bp + 1024);
            short8 b3 = *(const short8*)(bp + 1536);
            floatx4 C = {0.f, 0.f, 0.f, 0.f};
            C = __builtin_amdgcn_mfma_f32_16x16x32_bf16(a1[0], b0, C, 0, 0, 0);
            C = __builtin_amdgcn_mfma_f32_16x16x32_bf16(a1[1], b1, C, 0, 0, 0);
            C = __builtin_amdgcn_mfma_f32_16x16x32_bf16(a1[2], b2, C, 0, 0, 0);
            C = __builtin_amdgcn_mfma_f32_16x16x32_bf16(a1[3], b3, C, 0, 0, 0);
            int n = t * 16 + ln;
            float bias = fc_b1[n];
            #pragma unroll
            for (int r = 0; r < 4; ++r)
                s_H[(rbase + r) * 136 + n] = f2bf(fmaxf(C[r] + bias, 0.f));
        }
    }
    __syncthreads();

    // A2 fragments stay in registers for the whole main loop
    short8 a2[4];
    {
        const short* hp = s_H + (ew + ln) * 136 + qd * 8;
        #pragma unroll
        for (int kt = 0; kt < 4; ++kt) a2[kt] = *(const short8*)(hp + kt * 32);
    }

    // ---- main loop: 160 N-tiles, no barriers, coalesced b-frag loads ----
    float r0lo[4] = {0,0,0,0}, r0hi[4] = {0,0,0,0};
    float r1lo[4] = {0,0,0,0}, r1hi[4] = {0,0,0,0};
    float r3[4]   = {0,0,0,0};
    float r4[4][3] = {{0,0,0},{0,0,0},{0,0,0},{0,0,0}};
    float r5[4][3] = {{0,0,0},{0,0,0},{0,0,0},{0,0,0}};

    const short* wbase = w2f + lane * 8;

    auto tileC = [&](int t) -> floatx4 {
        const short* bp = wbase + (size_t)t * 2048;
        short8 b0 = *(const short8*)bp;
        short8 b1 = *(const short8*)(bp + 512);
        short8 b2 = *(const short8*)(bp + 1024);
        short8 b3 = *(const short8*)(bp + 1536);
        floatx4 C = {0.f, 0.f, 0.f, 0.f};
        C = __builtin_amdgcn_mfma_f32_16x16x32_bf16(a2[0], b0, C, 0, 0, 0);
        C = __builtin_amdgcn_mfma_f32_16x16x32_bf16(a2[1], b1, C, 0, 0, 0);
        C = __builtin_amdgcn_mfma_f32_16x16x32_bf16(a2[2], b2, C, 0, 0, 0);
        C = __builtin_amdgcn_mfma_f32_16x16x32_bf16(a2[3], b3, C, 0, 0, 0);
        float bias = fc_b2[t * 16 + ln];
        C[0] += bias; C[1] += bias; C[2] += bias; C[3] += bias;
        return C;
    };

    // region 1: w1[u<32][w<32] -> out0          (tiles 0..63)
    #pragma unroll 2
    for (int u = 0; u < 32; ++u) {
        floatx4 Clo = tileC(2 * u);
        floatx4 Chi = tileC(2 * u + 1);
        #pragma unroll
        for (int r = 0; r < 4; ++r) {
            float a = s_x0[(rbase + r) * 33 + u];
            r0lo[r] += a * Clo[r];
            r0hi[r] += a * Chi[r];
        }
    }
    // region 2: w2[u<16][w<32] -> out0          (tiles 64..95)
    #pragma unroll 2
    for (int u = 0; u < 16; ++u) {
        floatx4 Clo = tileC(64 + 2 * u);
        floatx4 Chi = tileC(65 + 2 * u);
        #pragma unroll
        for (int r = 0; r < 4; ++r) {
            float a = s_x1d[(rbase + r) * 17 + u];
            r1lo[r] += a * Clo[r];
            r1hi[r] += a * Chi[r];
        }
    }
    // region 3: w3[u<32][w<16] -> out1 (sh1 term)  (tiles 96..127)
    #pragma unroll 2
    for (int u = 0; u < 32; ++u) {
        floatx4 C = tileC(96 + u);
        #pragma unroll
        for (int r = 0; r < 4; ++r)
            r3[r] += s_x0[(rbase + r) * 33 + u] * C[r];
    }
    // region 4: w4[u<16][w<16] -> out1 (sh0 term)  (tiles 128..143)
    #pragma unroll 2
    for (int u = 0; u < 16; ++u) {
        floatx4 C = tileC(128 + u);
        #pragma unroll
        for (int r = 0; r < 4; ++r) {
            const float* xp = &s_x1[(rbase + r) * 49 + u * 3];
            r4[r][0] += xp[0] * C[r];
            r4[r][1] += xp[1] * C[r];
            r4[r][2] += xp[2] * C[r];
        }
    }
    // region 5: w5[u<16][w<16] -> out1 (cross term; Σ_u x1·C here, ×sh1 in
    // epilogue — cross is linear in u)            (tiles 144..159)
    #pragma unroll 2
    for (int u = 0; u < 16; ++u) {
        floatx4 C = tileC(144 + u);
        #pragma unroll
        for (int r = 0; r < 4; ++r) {
            const float* xp = &s_x1[(rbase + r) * 49 + u * 3];
            r5[r][0] += xp[0] * C[r];
            r5[r][1] += xp[1] * C[r];
            r5[r][2] += xp[2] * C[r];
        }
    }

    // ---- epilogue: atomic scatter by src ----
    #pragma unroll
    for (int r = 0; r < 4; ++r) {
        int e = rbase + r;
        float sh0 = s_sh[e*4], sa = s_sh[e*4+1], sb = s_sh[e*4+2], sc = s_sh[e*4+3];
        int base = s_src[e] * 80;
        atomicAdd(&accum[base + ln],      C0f * (sh0 * r0lo[r] + IS3 * r1lo[r]));
        atomicAdd(&accum[base + 16 + ln], C0f * (sh0 * r0hi[r] + IS3 * r1hi[r]));
        float t3 = C1f * IS3 * r3[r];
        float s0 = C1f * IS3 * sh0;
        float c6 = C1f * IS6;
        float v50 = r5[r][1] * sc - r5[r][2] * sb;   // (Σ x1·C) x sh1
        float v51 = r5[r][2] * sa - r5[r][0] * sc;
        float v52 = r5[r][0] * sb - r5[r][1] * sa;
        atomicAdd(&accum[base + 32 + ln*3 + 0], sa * t3 + s0 * r4[r][0] + c6 * v50);
        atomicAdd(&accum[base + 32 + ln*3 + 1], sb * t3 + s0 * r4[r][1] + c6 * v51);
        atomicAdd(&accum[base + 32 + ln*3 + 2], sc * t3 + s0 * r4[r][2] + c6 * v52);
    }
}

// Per-node: mean-divide, residual, equivariant layernorm. In-place on d_out.
__global__ __launch_bounds__(256)
void node_kernel(const float* __restrict__ node_attr,
                 const float* __restrict__ mean_shift,
                 const float* __restrict__ aw,
                 const float* __restrict__ ab,
                 const float* __restrict__ cnt,
                 float* __restrict__ out)
{
    int n = blockIdx.x * blockDim.x + threadIdx.x;
    if (n >= N_NODES) return;
    float inv = 1.0f / fmaxf(cnt[n], 1.0f);
    size_t base = (size_t)n * 80;
    float v[80];
    const float4* o4 = (const float4*)(out + base);
    const float4* a4 = (const float4*)(node_attr + base);
    #pragma unroll
    for (int i = 0; i < 20; ++i) {
        float4 o = o4[i], a = a4[i];
        v[4*i+0] = o.x * inv + a.x;
        v[4*i+1] = o.y * inv + a.y;
        v[4*i+2] = o.z * inv + a.z;
        v[4*i+3] = o.w * inv + a.w;
    }

    float m0 = 0.f;
    #pragma unroll
    for (int u = 0; u < 32; ++u) m0 += v[u];
    m0 *= (1.0f / 32.0f);
    float n0 = 0.f;
    #pragma unroll
    for (int u = 0; u < 32; ++u) {
        float f = v[u] - m0 * mean_shift[u];
        v[u] = f;
        n0 += f * f;
    }
    n0 = rsqrtf(n0 * (1.0f / 32.0f) + EPS_LN);
    #pragma unroll
    for (int u = 0; u < 32; ++u) v[u] = v[u] * (n0 * aw[u]) + ab[u];

    float m1[3] = {0.f, 0.f, 0.f};
    #pragma unroll
    for (int u = 0; u < 16; ++u)
        #pragma unroll
        for (int i = 0; i < 3; ++i) m1[i] += v[32 + u*3 + i];
    #pragma unroll
    for (int i = 0; i < 3; ++i) m1[i] *= (1.0f / 16.0f);
    float n1 = 0.f;
    #pragma unroll
    for (int u = 0; u < 16; ++u)
        #pragma unroll
        for (int i = 0; i < 3; ++i) {
            float f = v[32 + u*3 + i] - m1[i] * mean_shift[32 + u];
            v[32 + u*3 + i] = f;
            n1 += f * f;
        }
    n1 = rsqrtf(n1 * (1.0f / 48.0f) + EPS_LN);
    #pragma unroll
    for (int u = 0; u < 16; ++u)
        #pragma unroll
        for (int i = 0; i < 3; ++i)
            v[32 + u*3 + i] *= (n1 * aw[32 + u]);

    float4* w4 = (float4*)(out + base);
    #pragma unroll
    for (int i = 0; i < 20; ++i) {
        float4 o; o.x = v[4*i]; o.y = v[4*i+1]; o.z = v[4*i+2]; o.w = v[4*i+3];
        w4[i] = o;
    }
}

extern "C" void kernel_launch(void* const* d_in, const int* in_sizes, int n_in,
                              void* d_out, int out_size, void* d_ws, size_t ws_size,
                              hipStream_t stream) {
    const float* node_attr  = (const float*)d_in[0];
    const float* edge_attr  = (const float*)d_in[1];
    const float* edge_sh    = (const float*)d_in[2];
    const float* fc_w1      = (const float*)d_in[3];
    const float* fc_b1      = (const float*)d_in[4];
    const float* fc_w2      = (const float*)d_in[5];
    const float* fc_b2      = (const float*)d_in[6];
    const float* mean_shift = (const float*)d_in[7];
    const float* aw         = (const float*)d_in[8];
    const float* ab         = (const float*)d_in[9];
    const int*   edge_index = (const int*)d_in[10];
    float* out = (float*)d_out;

    short* w1f = (short*)((char*)d_ws + W1F_OFF);
    short* w2f = (short*)((char*)d_ws + W2F_OFF);
    float* cnt = (float*)((char*)d_ws + CNT_OFF);

    hipMemsetAsync(d_out, 0, (size_t)N_NODES * 80 * sizeof(float), stream);
    hipMemsetAsync(cnt, 0, (size_t)N_NODES * sizeof(float), stream);

    prep_kernel<<<(2048 + 40960 + 255) / 256, 256, 0, stream>>>(fc_w1, fc_w2, w1f, w2f);
    edge_kernel<<<EBLK, 256, 0, stream>>>(node_attr, edge_attr, edge_sh,
                                          fc_b1, fc_b2, edge_index,
                                          w1f, w2f, out, cnt);
    node_kernel<<<(N_NODES + 255) / 256, 256, 0, stream>>>(node_attr, mean_shift,
                                                           aw, ab, cnt, out);
}

// Round 5
// 364.499 us; speedup vs baseline: 8.7495x; 1.1697x over previous
//
#include <hip/hip_runtime.h>

typedef __attribute__((ext_vector_type(8))) short short8;
typedef __attribute__((ext_vector_type(4))) short bfx4;
typedef __attribute__((ext_vector_type(4))) float floatx4;

#define N_NODES 20000
#define N_EDGES 160000
#define TILE_E 64
#define EBLK (N_EDGES / TILE_E)   // 2500

#define C0f   0.14433756729740643f   // sqrt(1/48)
#define C1f   0.21650635094610965f   // sqrt(3/64)
#define IS3   0.5773502691896258f    // 1/sqrt(3)
#define IS6   0.4082482904638631f    // 1/sqrt(6)
#define EPS_LN 1e-5f

// ws layout (bytes):
//   [0, 32768)        w1f: W1 bf16, MFMA B-frag order
//   [32768, 688128)   w2f: W2 bf16, MFMA B-frag order
//   [688128, 768128)  cnt: N_NODES floats (zeroed by prep)
#define W1F_OFF 0
#define W2F_OFF 32768
#define CNT_OFF 688128

__device__ __forceinline__ short f2bf(float f) {   // fp32 -> bf16 RNE
    unsigned u = __float_as_uint(f);
    u += 0x7fff + ((u >> 16) & 1);
    return (short)(u >> 16);
}
__device__ __forceinline__ float bf2f(short s) {
    return __uint_as_float(((unsigned)(unsigned short)s) << 16);
}

__device__ __forceinline__ short8 load8_bf16(const float* p) {
    const float4* q = (const float4*)p;
    float4 f0 = q[0], f1 = q[1];
    short8 s;
    s[0]=f2bf(f0.x); s[1]=f2bf(f0.y); s[2]=f2bf(f0.z); s[3]=f2bf(f0.w);
    s[4]=f2bf(f1.x); s[5]=f2bf(f1.y); s[6]=f2bf(f1.z); s[7]=f2bf(f1.w);
    return s;
}

__device__ __forceinline__ floatx4 mfma4(const short8* a, short8 b0, short8 b1,
                                         short8 b2, short8 b3, float bias) {
    floatx4 C = {bias, bias, bias, bias};   // bias as C-init: free bias add
    C = __builtin_amdgcn_mfma_f32_16x16x32_bf16(a[0], b0, C, 0, 0, 0);
    C = __builtin_amdgcn_mfma_f32_16x16x32_bf16(a[1], b1, C, 0, 0, 0);
    C = __builtin_amdgcn_mfma_f32_16x16x32_bf16(a[2], b2, C, 0, 0, 0);
    C = __builtin_amdgcn_mfma_f32_16x16x32_bf16(a[3], b3, C, 0, 0, 0);
    return C;
}

// W1/W2 -> bf16 fragment order; also zero cnt.
__global__ __launch_bounds__(256)
void prep_kernel(const float* __restrict__ fc_w1, const float* __restrict__ fc_w2,
                 short* __restrict__ w1f, short* __restrict__ w2f,
                 float* __restrict__ cnt) {
    int g = blockIdx.x * 256 + threadIdx.x;
    if (g < N_NODES) cnt[g] = 0.0f;
    if (g < 2048) {                      // W1: t<8, kt<4
        int ln = g & 15, qd = (g >> 4) & 3, kt = (g >> 6) & 3, t = g >> 8;
        int n = t * 16 + ln, kb = kt * 32 + qd * 8;
        short8 s;
        #pragma unroll
        for (int j = 0; j < 8; ++j) s[j] = f2bf(fc_w1[(kb + j) * 128 + n]);
        *(short8*)(w1f + g * 8) = s;
        return;
    }
    int g2 = g - 2048;
    if (g2 < 40960) {                    // W2: t<160, kt<4
        int ln = g2 & 15, qd = (g2 >> 4) & 3, kt = (g2 >> 6) & 3, t = g2 >> 8;
        int n = t * 16 + ln, kb = kt * 32 + qd * 8;
        short8 s;
        #pragma unroll
        for (int j = 0; j < 8; ++j) s[j] = f2bf(fc_w2[(kb + j) * 2560 + n]);
        *(short8*)(w2f + g2 * 8) = s;
    }
}

__global__ __launch_bounds__(128, 2)
void edge_kernel(const float* __restrict__ node_attr,
                 const float* __restrict__ edge_attr,
                 const float* __restrict__ edge_sh,
                 const float* __restrict__ fc_b1,
                 const float* __restrict__ fc_b2,
                 const int*   __restrict__ edge_index,
                 const short* __restrict__ w1f,
                 const short* __restrict__ w2f,
                 float* __restrict__ accum,   // d_out, pre-zeroed
                 float* __restrict__ cnt)     // zeroed by prep
{
    __shared__ short s_H[64 * 136];     // hidden activations bf16
    __shared__ short s_x0t[32 * 64];    // transposed bf16: [u][e]
    __shared__ short s_x1t[48 * 64];    // [u*3+i][e]
    __shared__ short s_x1dt[16 * 64];   // [u][e]
    __shared__ float s_sh[64 * 4];
    __shared__ int   s_src[64];
    __shared__ int   s_dst[64];

    const int tid = threadIdx.x;
    const int e0  = blockIdx.x * TILE_E;

    // ---- phase A: indices, sh ----
    if (tid < 64) {
        int s = edge_index[e0 + tid];
        int d = edge_index[N_EDGES + e0 + tid];
        s_src[tid] = s; s_dst[tid] = d;
        atomicAdd(&cnt[s], 1.0f);
    }
    s_sh[tid]       = edge_sh[(size_t)e0 * 4 + tid];
    s_sh[tid + 128] = edge_sh[(size_t)e0 * 4 + tid + 128];
    __syncthreads();

    // gather (transposed bf16) + x1.sh1 dot
    #pragma unroll
    for (int i = 0; i < 40; ++i) {
        int f = tid + i * 128;
        int e = f / 80, c = f % 80;
        float v = node_attr[(size_t)s_dst[e] * 80 + c];
        if (c < 32) s_x0t[c * 64 + e] = f2bf(v);
        else        s_x1t[(c - 32) * 64 + e] = f2bf(v);
    }
    #pragma unroll
    for (int i = 0; i < 8; ++i) {
        int it = tid + i * 128;
        int e = it >> 4, u = it & 15;
        const float* xp = node_attr + (size_t)s_dst[e] * 80 + 32 + u * 3;
        float d = xp[0] * s_sh[e*4+1] + xp[1] * s_sh[e*4+2] + xp[2] * s_sh[e*4+3];
        s_x1dt[u * 64 + e] = f2bf(d);
    }
    __syncthreads();

    // ---- per-wave identity: wave owns 32 edges as 2 MFMA groups ----
    const int lane = tid & 63;
    const int wv   = tid >> 6;
    const int ln   = lane & 15;
    const int qd   = lane >> 4;
    const int eb0  = wv * 32 + qd * 4;        // group 0 C-row base
    const int eb1  = eb0 + 16;                // group 1

    // ---- MLP1: h = relu(EA @ W1 + b1) via MFMA ----
    {
        short8 a1[2][4];
        #pragma unroll
        for (int g = 0; g < 2; ++g) {
            const float* ap = edge_attr + (size_t)(e0 + wv*32 + g*16 + ln) * 128 + qd * 8;
            #pragma unroll
            for (int kt = 0; kt < 4; ++kt) a1[g][kt] = load8_bf16(ap + kt * 32);
        }
        #pragma unroll
        for (int t = 0; t < 8; ++t) {
            const short* bp = w1f + t * 2048 + lane * 8;
            short8 b0 = *(const short8*)bp;
            short8 b1 = *(const short8*)(bp + 512);
            short8 b2 = *(const short8*)(bp + 1024);
            short8 b3 = *(const short8*)(bp + 1536);
            float bias = fc_b1[t * 16 + ln];
            #pragma unroll
            for (int g = 0; g < 2; ++g) {
                floatx4 C = mfma4(a1[g], b0, b1, b2, b3, bias);
                #pragma unroll
                for (int r = 0; r < 4; ++r)
                    s_H[(wv*32 + g*16 + qd*4 + r) * 136 + t*16 + ln] = f2bf(fmaxf(C[r], 0.f));
            }
        }
    }
    __syncthreads();

    // A2 fragments (live across the whole main loop)
    short8 a2[2][4];
    #pragma unroll
    for (int g = 0; g < 2; ++g) {
        const short* hp = s_H + (wv*32 + g*16 + ln) * 136 + qd * 8;
        #pragma unroll
        for (int kt = 0; kt < 4; ++kt) a2[g][kt] = *(const short8*)(hp + kt * 32);
    }

    const short* wbase = w2f + lane * 8;

    // ================= PHASE 1: out0 (regions 1-2) =================
    float r0lo[2][4] = {}, r0hi[2][4] = {}, r1lo[2][4] = {}, r1hi[2][4] = {};

    #pragma unroll 2
    for (int u = 0; u < 32; ++u) {       // region 1: tiles 2u, 2u+1
        const short* bp = wbase + (size_t)(2*u) * 2048;
        short8 L0 = *(const short8*)bp,          L1 = *(const short8*)(bp + 512);
        short8 L2 = *(const short8*)(bp + 1024), L3 = *(const short8*)(bp + 1536);
        short8 H0 = *(const short8*)(bp + 2048), H1 = *(const short8*)(bp + 2560);
        short8 H2 = *(const short8*)(bp + 3072), H3 = *(const short8*)(bp + 3584);
        float blo = fc_b2[2*u*16 + ln], bhi = fc_b2[2*u*16 + 16 + ln];
        #pragma unroll
        for (int g = 0; g < 2; ++g) {
            floatx4 Clo = mfma4(a2[g], L0, L1, L2, L3, blo);
            floatx4 Chi = mfma4(a2[g], H0, H1, H2, H3, bhi);
            bfx4 xs = *(const bfx4*)(s_x0t + u*64 + (g ? eb1 : eb0));
            #pragma unroll
            for (int r = 0; r < 4; ++r) {
                float a = bf2f(xs[r]);
                r0lo[g][r] += a * Clo[r];
                r0hi[g][r] += a * Chi[r];
            }
        }
    }
    #pragma unroll 2
    for (int u = 0; u < 16; ++u) {       // region 2: tiles 64+2u, 65+2u
        const short* bp = wbase + (size_t)(64 + 2*u) * 2048;
        short8 L0 = *(const short8*)bp,          L1 = *(const short8*)(bp + 512);
        short8 L2 = *(const short8*)(bp + 1024), L3 = *(const short8*)(bp + 1536);
        short8 H0 = *(const short8*)(bp + 2048), H1 = *(const short8*)(bp + 2560);
        short8 H2 = *(const short8*)(bp + 3072), H3 = *(const short8*)(bp + 3584);
        float blo = fc_b2[(64 + 2*u)*16 + ln], bhi = fc_b2[(64 + 2*u)*16 + 16 + ln];
        #pragma unroll
        for (int g = 0; g < 2; ++g) {
            floatx4 Clo = mfma4(a2[g], L0, L1, L2, L3, blo);
            floatx4 Chi = mfma4(a2[g], H0, H1, H2, H3, bhi);
            bfx4 xs = *(const bfx4*)(s_x1dt + u*64 + (g ? eb1 : eb0));
            #pragma unroll
            for (int r = 0; r < 4; ++r) {
                float a = bf2f(xs[r]);
                r1lo[g][r] += a * Clo[r];
                r1hi[g][r] += a * Chi[r];
            }
        }
    }
    // phase-1 epilogue: out0 scatter
    #pragma unroll
    for (int g = 0; g < 2; ++g)
        #pragma unroll
        for (int r = 0; r < 4; ++r) {
            int e = (g ? eb1 : eb0) + r;
            float sh0 = s_sh[e*4];
            int base = s_src[e] * 80;
            atomicAdd(&accum[base + ln],      C0f * (sh0 * r0lo[g][r] + IS3 * r1lo[g][r]));
            atomicAdd(&accum[base + 16 + ln], C0f * (sh0 * r0hi[g][r] + IS3 * r1hi[g][r]));
        }

    // ================= PHASE 2: out1 (regions 3-5) =================
    float r3[2][4] = {};
    float r4[2][4][3] = {};
    float r5[2][4][3] = {};

    #pragma unroll 2
    for (int u = 0; u < 32; ++u) {       // region 3: tile 96+u
        const short* bp = wbase + (size_t)(96 + u) * 2048;
        short8 b0 = *(const short8*)bp,          b1 = *(const short8*)(bp + 512);
        short8 b2 = *(const short8*)(bp + 1024), b3 = *(const short8*)(bp + 1536);
        float bias = fc_b2[(96 + u)*16 + ln];
        #pragma unroll
        for (int g = 0; g < 2; ++g) {
            floatx4 C = mfma4(a2[g], b0, b1, b2, b3, bias);
            bfx4 xs = *(const bfx4*)(s_x0t + u*64 + (g ? eb1 : eb0));
            #pragma unroll
            for (int r = 0; r < 4; ++r)
                r3[g][r] += bf2f(xs[r]) * C[r];
        }
    }
    for (int u = 0; u < 16; ++u) {       // regions 4+5: tiles 128+u, 144+u share x1 reads
        const short* bp4 = wbase + (size_t)(128 + u) * 2048;
        short8 F0 = *(const short8*)bp4,          F1 = *(const short8*)(bp4 + 512);
        short8 F2 = *(const short8*)(bp4 + 1024), F3 = *(const short8*)(bp4 + 1536);
        const short* bp5 = wbase + (size_t)(144 + u) * 2048;
        short8 G0 = *(const short8*)bp5,          G1 = *(const short8*)(bp5 + 512);
        short8 G2 = *(const short8*)(bp5 + 1024), G3 = *(const short8*)(bp5 + 1536);
        float b4 = fc_b2[(128 + u)*16 + ln], b5 = fc_b2[(144 + u)*16 + ln];
        #pragma unroll
        for (int g = 0; g < 2; ++g) {
            floatx4 C4 = mfma4(a2[g], F0, F1, F2, F3, b4);
            floatx4 C5 = mfma4(a2[g], G0, G1, G2, G3, b5);
            int eb = (g ? eb1 : eb0);
            bfx4 x0s = *(const bfx4*)(s_x1t + (u*3 + 0)*64 + eb);
            bfx4 x1s = *(const bfx4*)(s_x1t + (u*3 + 1)*64 + eb);
            bfx4 x2s = *(const bfx4*)(s_x1t + (u*3 + 2)*64 + eb);
            #pragma unroll
            for (int r = 0; r < 4; ++r) {
                float a0 = bf2f(x0s[r]), a1 = bf2f(x1s[r]), a2v = bf2f(x2s[r]);
                r4[g][r][0] += a0 * C4[r];  r5[g][r][0] += a0 * C5[r];
                r4[g][r][1] += a1 * C4[r];  r5[g][r][1] += a1 * C5[r];
                r4[g][r][2] += a2v * C4[r]; r5[g][r][2] += a2v * C5[r];
            }
        }
    }
    // phase-2 epilogue: out1 scatter (region-5 cross applied here; linear in u)
    #pragma unroll
    for (int g = 0; g < 2; ++g)
        #pragma unroll
        for (int r = 0; r < 4; ++r) {
            int e = (g ? eb1 : eb0) + r;
            float sh0 = s_sh[e*4], sa = s_sh[e*4+1], sb = s_sh[e*4+2], sc = s_sh[e*4+3];
            int base = s_src[e] * 80;
            float t3 = C1f * IS3 * r3[g][r];
            float s0 = C1f * IS3 * sh0;
            float c6 = C1f * IS6;
            float v50 = r5[g][r][1] * sc - r5[g][r][2] * sb;
            float v51 = r5[g][r][2] * sa - r5[g][r][0] * sc;
            float v52 = r5[g][r][0] * sb - r5[g][r][1] * sa;
            atomicAdd(&accum[base + 32 + ln*3 + 0], sa * t3 + s0 * r4[g][r][0] + c6 * v50);
            atomicAdd(&accum[base + 32 + ln*3 + 1], sb * t3 + s0 * r4[g][r][1] + c6 * v51);
            atomicAdd(&accum[base + 32 + ln*3 + 2], sc * t3 + s0 * r4[g][r][2] + c6 * v52);
        }
}

// Per-node: mean-divide, residual, equivariant layernorm. In-place on d_out.
__global__ __launch_bounds__(256)
void node_kernel(const float* __restrict__ node_attr,
                 const float* __restrict__ mean_shift,
                 const float* __restrict__ aw,
                 const float* __restrict__ ab,
                 const float* __restrict__ cnt,
                 float* __restrict__ out)
{
    int n = blockIdx.x * blockDim.x + threadIdx.x;
    if (n >= N_NODES) return;
    float inv = 1.0f / fmaxf(cnt[n], 1.0f);
    size_t base = (size_t)n * 80;
    float v[80];
    const float4* o4 = (const float4*)(out + base);
    const float4* a4 = (const float4*)(node_attr + base);
    #pragma unroll
    for (int i = 0; i < 20; ++i) {
        float4 o = o4[i], a = a4[i];
        v[4*i+0] = o.x * inv + a.x;
        v[4*i+1] = o.y * inv + a.y;
        v[4*i+2] = o.z * inv + a.z;
        v[4*i+3] = o.w * inv + a.w;
    }

    float m0 = 0.f;
    #pragma unroll
    for (int u = 0; u < 32; ++u) m0 += v[u];
    m0 *= (1.0f / 32.0f);
    float n0 = 0.f;
    #pragma unroll
    for (int u = 0; u < 32; ++u) {
        float f = v[u] - m0 * mean_shift[u];
        v[u] = f;
        n0 += f * f;
    }
    n0 = rsqrtf(n0 * (1.0f / 32.0f) + EPS_LN);
    #pragma unroll
    for (int u = 0; u < 32; ++u) v[u] = v[u] * (n0 * aw[u]) + ab[u];

    float m1[3] = {0.f, 0.f, 0.f};
    #pragma unroll
    for (int u = 0; u < 16; ++u)
        #pragma unroll
        for (int i = 0; i < 3; ++i) m1[i] += v[32 + u*3 + i];
    #pragma unroll
    for (int i = 0; i < 3; ++i) m1[i] *= (1.0f / 16.0f);
    float n1 = 0.f;
    #pragma unroll
    for (int u = 0; u < 16; ++u)
        #pragma unroll
        for (int i = 0; i < 3; ++i) {
            float f = v[32 + u*3 + i] - m1[i] * mean_shift[32 + u];
            v[32 + u*3 + i] = f;
            n1 += f * f;
        }
    n1 = rsqrtf(n1 * (1.0f / 48.0f) + EPS_LN);
    #pragma unroll
    for (int u = 0; u < 16; ++u)
        #pragma unroll
        for (int i = 0; i < 3; ++i)
            v[32 + u*3 + i] *= (n1 * aw[32 + u]);

    float4* w4 = (float4*)(out + base);
    #pragma unroll
    for (int i = 0; i < 20; ++i) {
        float4 o; o.x = v[4*i]; o.y = v[4*i+1]; o.z = v[4*i+2]; o.w = v[4*i+3];
        w4[i] = o;
    }
}

extern "C" void kernel_launch(void* const* d_in, const int* in_sizes, int n_in,
                              void* d_out, int out_size, void* d_ws, size_t ws_size,
                              hipStream_t stream) {
    const float* node_attr  = (const float*)d_in[0];
    const float* edge_attr  = (const float*)d_in[1];
    const float* edge_sh    = (const float*)d_in[2];
    const float* fc_w1      = (const float*)d_in[3];
    const float* fc_b1      = (const float*)d_in[4];
    const float* fc_w2      = (const float*)d_in[5];
    const float* fc_b2      = (const float*)d_in[6];
    const float* mean_shift = (const float*)d_in[7];
    const float* aw         = (const float*)d_in[8];
    const float* ab         = (const float*)d_in[9];
    const int*   edge_index = (const int*)d_in[10];
    float* out = (float*)d_out;

    short* w1f = (short*)((char*)d_ws + W1F_OFF);
    short* w2f = (short*)((char*)d_ws + W2F_OFF);
    float* cnt = (float*)((char*)d_ws + CNT_OFF);

    (void)hipMemsetAsync(d_out, 0, (size_t)N_NODES * 80 * sizeof(float), stream);

    prep_kernel<<<(2048 + 40960 + 255) / 256, 256, 0, stream>>>(fc_w1, fc_w2, w1f, w2f, cnt);
    edge_kernel<<<EBLK, 128, 0, stream>>>(node_attr, edge_attr, edge_sh,
                                          fc_b1, fc_b2, edge_index,
                                          w1f, w2f, out, cnt);
    node_kernel<<<(N_NODES + 255) / 256, 256, 0, stream>>>(node_attr, mean_shift,
                                                           aw, ab, cnt, out);
}